// Round 3
// baseline (186.557 us; speedup 1.0000x reference)
//
#include <hip/hip_runtime.h>
#include <hip/hip_fp16.h>

typedef _Float16 half8  __attribute__((ext_vector_type(8)));
typedef _Float16 half4_t __attribute__((ext_vector_type(4)));
typedef _Float16 half2_t __attribute__((ext_vector_type(2)));
typedef float f32x4 __attribute__((ext_vector_type(4)));

namespace {
constexpr int NT = 256;
constexpr int NPIX = 225;
constexpr int PCODE_C = 2380;

// A[6][15 rows][17 cols] half8 slots; col0/col16 = zero x-pads, rows = pixel y
constexpr int AROW = 272;   // 17 slots * 16 B
constexpr int ACG  = 4080;  // 15 rows * 272

// ---- LDS layout (byte offsets, 16-aligned), 5 blocks/CU plan ----
// P1 writes A[0..5] (0..24480)
// phase a: conv cg4,5 reads A[4,5] -> Xc4/Xc5 fresh  (24480..31680)
// phase b: conv cg2,3 reads A[2,3] -> Xc2/Xc3 over A[4,5]
// phase c: conv cg0,1 reads A[0,1] -> Xc0/Xc1 over A[2,3]
// heads:  POLA0/1 over dead A[0,1]; all Xc* live
constexpr int OFF_A     = 0;        // 6*4080 = 24480
constexpr int OFF_POLA0 = 0;        // [15][17] = 4080 (head phase)
constexpr int OFF_POLA1 = 4080;
constexpr int OFF_XC0   = 8160;     // 225*16 = 3600 per cg
constexpr int OFF_XC1   = 11760;
constexpr int OFF_XC2   = 16320;
constexpr int OFF_XC3   = 19920;
constexpr int OFF_SV    = 23520;    // f32[32] (dead A[5] tail, head phase only)
constexpr int OFF_H1    = 23648;    // f32[32]
constexpr int OFF_H2    = 23776;    // f32[32]
constexpr int OFF_XC4   = 24480;
constexpr int OFF_XC5   = 28080;
constexpr int OFF_ZROW  = 31680;    // 272 B of zeros (y-edge clamp target)
constexpr int OFF_SLOTA = 31952;    // 320 B: 2 cg x (144 w + 16 b) f16
constexpr int OFF_SLOTB = 32272;    // 320 B
constexpr int SMEM_BYTES = 32592;   // rounds to 32768 -> 5 blocks/CU (163840 = 160 KiB)
}

__device__ __forceinline__ half2_t pkrtz(float a, float b) {
    return __builtin_bit_cast(half2_t, __builtin_amdgcn_cvt_pkrtz(a, b));
}
__device__ __forceinline__ void wave_fence() {
    asm volatile("s_waitcnt lgkmcnt(0)" ::: "memory");
}

__global__ __launch_bounds__(NT, 5) void patnet_kernel(
    const float* __restrict__ emb,
    const float* __restrict__ conv_w, const float* __restrict__ conv_b,
    const float* __restrict__ ppw_w,  const float* __restrict__ ppw_b,
    const float* __restrict__ pdw_w,  const float* __restrict__ pdw_b,
    const float* __restrict__ pf_w,
    const float* __restrict__ vpw_w,  const float* __restrict__ vpw_b,
    const float* __restrict__ vl1_w,  const float* __restrict__ vl1_b,
    const float* __restrict__ vl2_w,  const float* __restrict__ vl2_b,
    const float* __restrict__ vf_w,   const float* __restrict__ vf_b,
    const int* __restrict__ sparse,   const int* __restrict__ board,
    float* __restrict__ out, int batch)
{
    __shared__ __align__(16) unsigned char smem[SMEM_BYTES];
    const int tid  = threadIdx.x;
    const int b    = blockIdx.x;
    const int lane = tid & 63;
    const int wave = tid >> 6;

    // ---- issue code loads first (deep prefetch) ----
    int c0 = 0, c1 = 0;
    if (tid < NPIX) {
        int s10 = sparse[b * 2700 + 10 * NPIX + tid];
        int s11 = sparse[b * 2700 + 11 * NPIX + tid];
        int b0  = board[b * 450 + tid];
        int b1  = board[b * 450 + NPIX + tid];
        c0 = (b0 > 0) ? PCODE_C : s10;
        c1 = ((b1 > 0) ? PCODE_C : s11) + (PCODE_C + 1);
    }

    // stage 2 cgs of (dw weights + bias) transposed into a 320 B slot.
    // slot halfs: cgl*80 + t*8 + j (w, t=0..8), cgl*80 + 72 + j (bias)
    auto stage_w = [&](int slotOff, const float* wsrc, const float* bsrc, int cgbase) {
        int i = tid - 96;
        if (i >= 0 && i < 160) {
            int cgl = i / 80, r = i - cgl * 80;
            _Float16 v;
            if (r < 72) {
                int t = r >> 3, j = r & 7;
                v = (_Float16)wsrc[((cgbase + cgl) * 8 + j) * 9 + t];
            } else {
                v = (_Float16)bsrc[(cgbase + cgl) * 8 + (r - 72)];
            }
            ((_Float16*)(smem + slotOff))[i] = v;
        }
    };

    // ---- P0: lanes 96..255 stage slot A (cg4,5); lanes 0..95 zero pads ----
    stage_w(OFF_SLOTA, conv_w, conv_b, 4);
    if (tid < 96) {
        for (int i = tid; i < 197; i += 96) {
            unsigned char* dst;
            if (i < 180) {            // A col pads: cols 0,16 x rows 0..14 x 6 cg
                int cg = i / 30, r = i - cg * 30;
                int row = r >> 1, colB = (r & 1) * 256;
                dst = smem + OFF_A + cg * ACG + row * AROW + colB;
            } else {                  // zero row: 17 slots
                dst = smem + OFF_ZROW + (i - 180) * 16;
            }
            *(half8*)dst = (half8)(_Float16)0.f;
        }
    }

    // ---- P1: embedding gather + sum -> A interior (rows 0..14, cols 1..15) ----
    if (tid < NPIX) {
        const float* e0 = emb + c0 * 48;
        const float* e1 = emb + c1 * 48;
        int y = tid / 15, x = tid - y * 15;
        unsigned char* abase = smem + OFF_A + y * AROW + (x + 1) * 16;
        #pragma unroll
        for (int g = 0; g < 6; g++) {
            f32x4 x0 = *(const f32x4*)(e0 + g * 8);
            f32x4 x1 = *(const f32x4*)(e0 + g * 8 + 4);
            f32x4 y0 = *(const f32x4*)(e1 + g * 8);
            f32x4 y1 = *(const f32x4*)(e1 + g * 8 + 4);
            f32x4 s0 = x0 + y0, s1 = x1 + y1;
            half2_t q0 = pkrtz(s0.x, s0.y), q1 = pkrtz(s0.z, s0.w);
            half2_t q2 = pkrtz(s1.x, s1.y), q3 = pkrtz(s1.z, s1.w);
            half8 hv = {q0[0], q0[1], q1[0], q1[1], q2[0], q2[1], q3[0], q3[1]};
            *(half8*)(abase + g * ACG) = hv;
        }
    }
    __syncthreads();

    // ---- conv 3x3 depthwise: 3 phases x 2 cgs; 90 strip-tasks per phase ----
    auto do_strip = [&](int t, int cgbase, int slotOff, int xBase) {
        int cgl = t / 45, rem = t - cgl * 45;
        int y = rem / 3, s = rem - y * 3;
        const unsigned char* wb = smem + slotOff + cgl * 160;
        half8 wv[9];
        #pragma unroll
        for (int i = 0; i < 9; i++) wv[i] = *(const half8*)(wb + i * 16);
        half8 bias = *(const half8*)(wb + 144);
        half8 acc[5] = {bias, bias, bias, bias, bias};
        const unsigned char* abase = smem + OFF_A + (cgbase + cgl) * ACG;
        const unsigned char* r0 = (y >= 1)  ? abase + (y - 1) * AROW : smem + OFF_ZROW;
        const unsigned char* r1 = abase + y * AROW;
        const unsigned char* r2 = (y <= 13) ? abase + (y + 1) * AROW : smem + OFF_ZROW;
        int xo = s * 80;              // strip start col * 16
        #pragma unroll
        for (int c = 0; c < 7; c++) {
            half8 v0 = *(const half8*)(r0 + xo + c * 16);
            half8 v1 = *(const half8*)(r1 + xo + c * 16);
            half8 v2 = *(const half8*)(r2 + xo + c * 16);
            #pragma unroll
            for (int o = 0; o < 5; o++) {
                int kx = c - o;
                if (kx >= 0 && kx <= 2) {
                    acc[o] = __builtin_elementwise_fma(v0, wv[kx],     acc[o]);
                    acc[o] = __builtin_elementwise_fma(v1, wv[3 + kx], acc[o]);
                    acc[o] = __builtin_elementwise_fma(v2, wv[6 + kx], acc[o]);
                }
            }
        }
        unsigned char* xw = smem + xBase + cgl * 3600 + (y * 15 + s * 5) * 16;
        #pragma unroll
        for (int o = 0; o < 5; o++)
            *(half8*)(xw + o * 16) = __builtin_elementwise_max(acc[o], (half8)(_Float16)0.f);
    };

    if (tid < 90) do_strip(tid, 4, OFF_SLOTA, OFF_XC4);   // phase a
    stage_w(OFF_SLOTB, conv_w, conv_b, 2);
    __syncthreads();
    if (tid < 90) do_strip(tid, 2, OFF_SLOTB, OFF_XC2);   // phase b
    stage_w(OFF_SLOTA, conv_w, conv_b, 0);
    __syncthreads();
    if (tid < 90) do_strip(tid, 0, OFF_SLOTA, OFF_XC0);   // phase c
    stage_w(OFF_SLOTB, pdw_w, pdw_b, 0);                  // policy dw -> slot B

    // ---- head-weight prefetch by ALL waves (loads fly during barrier drain) ----
    const int n = lane & 15, q = lane >> 4;
    const int cgp = lane & 1;                   // policy channel-group for this thread
    half8 af_p;
    {
        const float* wp = ppw_w + n * 16 + (q & 1) * 8;
        f32x4 w0 = *(const f32x4*)wp, w1 = *(const f32x4*)(wp + 4);
        half8 t = {(_Float16)w0.x, (_Float16)w0.y, (_Float16)w0.z, (_Float16)w0.w,
                   (_Float16)w1.x, (_Float16)w1.y, (_Float16)w1.z, (_Float16)w1.w};
        af_p = (q < 2) ? t : (half8)(_Float16)0.f;   // K zero-pad 16..31
    }
    f32x4 pb = *(const f32x4*)(ppw_b + q * 4);
    // per-thread pf slice: only the 4 pairs this thread's cgp needs
    half2_t pf0 = pkrtz(pf_w[cgp * 8 + 0], pf_w[cgp * 8 + 1]);
    half2_t pf1 = pkrtz(pf_w[cgp * 8 + 2], pf_w[cgp * 8 + 3]);
    half2_t pf2 = pkrtz(pf_w[cgp * 8 + 4], pf_w[cgp * 8 + 5]);
    half2_t pf3 = pkrtz(pf_w[cgp * 8 + 6], pf_w[cgp * 8 + 7]);
    half8 af0, af1;
    {
        const float* wp = vpw_w + n * 32 + q * 8;
        f32x4 w0 = *(const f32x4*)wp, w1 = *(const f32x4*)(wp + 4);
        af0 = half8{(_Float16)w0.x, (_Float16)w0.y, (_Float16)w0.z, (_Float16)w0.w,
                    (_Float16)w1.x, (_Float16)w1.y, (_Float16)w1.z, (_Float16)w1.w};
        const float* wp2 = vpw_w + (16 + n) * 32 + q * 8;
        f32x4 v0 = *(const f32x4*)wp2, v1 = *(const f32x4*)(wp2 + 4);
        af1 = half8{(_Float16)v0.x, (_Float16)v0.y, (_Float16)v0.z, (_Float16)v0.w,
                    (_Float16)v1.x, (_Float16)v1.y, (_Float16)v1.z, (_Float16)v1.w};
    }
    f32x4 vb0 = *(const f32x4*)(vpw_b + q * 4);
    f32x4 vb1 = *(const f32x4*)(vpw_b + 16 + q * 4);
    __syncthreads();

    // ================= head split: no more block barriers =================
    if (wave < 3) {
        // ---------------- policy path (waves 0,1,2) ----------------
        // zero POLA x-pads: cols 0,16 x rows 0..14 x 2 cg = 60 slots (idempotent per wave)
        if (lane < 60) {
            int cg = lane / 30, r = lane - cg * 30;
            int row = r >> 1, colB = (r & 1) * 256;
            *(half8*)(smem + OFF_POLA0 + cg * ACG + row * AROW + colB) = (half8)(_Float16)0.f;
        }
        // preload policy dw weights from slot B (staged during phase c)
        half8 wvp[9];
        #pragma unroll
        for (int t = 0; t < 9; t++) wvp[t] = *(const half8*)(smem + OFF_SLOTB + cgp * 160 + t * 16);
        half8 biasp = *(const half8*)(smem + OFF_SLOTB + cgp * 160 + 144);

        // ph3: 1x1 16->16 via MFMA; each wave computes every tile its ph4 rows need
        const int tlo = (wave == 0) ? 0 : ((wave == 1) ? 3 : 8);
        const int thi = (wave == 0) ? 6 : ((wave == 1) ? 11 : 15);
        const int cg3 = q >> 1;
        const int xbp = (q & 1) ? OFF_XC1 : OFF_XC0;
        for (int t = tlo; t < thi; t++) {
            int p = t * 16 + n;
            int pc = (p > 224) ? 224 : p;
            half8 bf = *(const half8*)(smem + xbp + pc * 16);
            f32x4 d = __builtin_amdgcn_mfma_f32_16x16x32_f16(af_p, bf, (f32x4)(0.f), 0, 0, 0);
            if (p < NPIX) {
                int y = p / 15, x = p - y * 15;
                half2_t lo = pkrtz(fmaxf(d.x + pb.x, 0.f), fmaxf(d.y + pb.y, 0.f));
                half2_t hi = pkrtz(fmaxf(d.z + pb.z, 0.f), fmaxf(d.w + pb.w, 0.f));
                half4_t hv = {lo[0], lo[1], hi[0], hi[1]};
                *(half4_t*)(smem + OFF_POLA0 + cg3 * ACG + y * AROW + (x + 1) * 16 + (q & 1) * 8) = hv;
            }
        }
        wave_fence();

        // ph4+ph5 fused: dw 3x3 + bias + relu + dot(pf) + pair-sum + store
        const int px0 = wave * 75;
        for (int i = 0; i < 3; i++) {
            int idx = i * 64 + lane;
            if (idx < 150) {
                int px = px0 + (idx >> 1);
                int y = px / 15, x = px - y * 15;
                const unsigned char* base = smem + OFF_POLA0 + cgp * ACG;
                const unsigned char* pm = (y > 0)  ? base + (y - 1) * AROW : smem + OFF_ZROW;
                const unsigned char* pz = base + y * AROW;
                const unsigned char* pp = (y < 14) ? base + (y + 1) * AROW : smem + OFF_ZROW;
                int xo = x * 16;
                half8 acc = biasp;
                acc = __builtin_elementwise_fma(*(const half8*)(pm + xo),      wvp[0], acc);
                acc = __builtin_elementwise_fma(*(const half8*)(pm + xo + 16), wvp[1], acc);
                acc = __builtin_elementwise_fma(*(const half8*)(pm + xo + 32), wvp[2], acc);
                acc = __builtin_elementwise_fma(*(const half8*)(pz + xo),      wvp[3], acc);
                acc = __builtin_elementwise_fma(*(const half8*)(pz + xo + 16), wvp[4], acc);
                acc = __builtin_elementwise_fma(*(const half8*)(pz + xo + 32), wvp[5], acc);
                acc = __builtin_elementwise_fma(*(const half8*)(pp + xo),      wvp[6], acc);
                acc = __builtin_elementwise_fma(*(const half8*)(pp + xo + 16), wvp[7], acc);
                acc = __builtin_elementwise_fma(*(const half8*)(pp + xo + 32), wvp[8], acc);
                acc = __builtin_elementwise_max(acc, (half8)(_Float16)0.f);
                float part = 0.f;
                part = __builtin_amdgcn_fdot2(half2_t{acc[0], acc[1]}, pf0, part, false);
                part = __builtin_amdgcn_fdot2(half2_t{acc[2], acc[3]}, pf1, part, false);
                part = __builtin_amdgcn_fdot2(half2_t{acc[4], acc[5]}, pf2, part, false);
                part = __builtin_amdgcn_fdot2(half2_t{acc[6], acc[7]}, pf3, part, false);
                float tot = part + __shfl_xor(part, 1, 64);
                if (cgp == 0) out[3 * batch + b * NPIX + px] = tot;
            }
        }
    } else {
        // ---------------- value path (wave 3, whole head in-wave) ----------------
        // B reads ch 16..47: q=0 -> Xc2, q=1 -> Xc3, q=2 -> Xc4, q=3 -> Xc5
        const int xb = (q < 2) ? (OFF_XC2 + q * 3600) : (OFF_XC4 + (q - 2) * 3600);
        f32x4 a0 = {0.f, 0.f, 0.f, 0.f}, a1 = {0.f, 0.f, 0.f, 0.f};
        for (int t = 0; t < 15; t++) {
            int p = t * 16 + n;
            int pc = (p > 224) ? 224 : p;
            half8 bf = *(const half8*)(smem + xb + pc * 16);
            f32x4 d0 = __builtin_amdgcn_mfma_f32_16x16x32_f16(af0, bf, (f32x4)(0.f), 0, 0, 0);
            f32x4 d1 = __builtin_amdgcn_mfma_f32_16x16x32_f16(af1, bf, (f32x4)(0.f), 0, 0, 0);
            if (p < NPIX) {
                #pragma unroll
                for (int r = 0; r < 4; r++) {
                    a0[r] += fmaxf(d0[r] + vb0[r], 0.f);
                    a1[r] += fmaxf(d1[r] + vb1[r], 0.f);
                }
            }
        }
        #pragma unroll
        for (int s = 1; s < 16; s <<= 1) {
            #pragma unroll
            for (int r = 0; r < 4; r++) {
                a0[r] += __shfl_xor(a0[r], s, 64);
                a1[r] += __shfl_xor(a1[r], s, 64);
            }
        }
        if (n == 0) {
            *(f32x4*)(smem + OFF_SV + q * 16)      = a0 * (1.f / 225.f);
            *(f32x4*)(smem + OFF_SV + 64 + q * 16) = a1 * (1.f / 225.f);
        }
        // FC weights staged ONE phase ahead (peak live = 64 weight VGPRs, no spill)
        const int o = lane & 31;
        f32x4 wA[8];
        float b1v = vl1_b[o], b2v = vl2_b[o], b3v = 0.f;
        #pragma unroll
        for (int g = 0; g < 8; g++) wA[g] = *(const f32x4*)(vl1_w + o * 32 + g * 4);
        wave_fence();                                  // SV visible wave-wide

        f32x4 wB[8];
        #pragma unroll
        for (int g = 0; g < 8; g++) wB[g] = *(const f32x4*)(vl2_w + o * 32 + g * 4);
        float acc1 = b1v;
        #pragma unroll
        for (int g = 0; g < 8; g++) {
            f32x4 sv = *(const f32x4*)(smem + OFF_SV + g * 16);
            acc1 += sv.x * wA[g].x + sv.y * wA[g].y + sv.z * wA[g].z + sv.w * wA[g].w;
        }
        acc1 = fmaxf(acc1, 0.f);
        if (lane < 32) *(float*)(smem + OFF_H1 + o * 4) = acc1;
        wave_fence();

        f32x4 wC[8];
        if (lane < 3) {
            b3v = vf_b[lane];
            #pragma unroll
            for (int g = 0; g < 8; g++) wC[g] = *(const f32x4*)(vf_w + lane * 32 + g * 4);
        }
        float acc2 = b2v;
        #pragma unroll
        for (int g = 0; g < 8; g++) {
            f32x4 hv = *(const f32x4*)(smem + OFF_H1 + g * 16);
            acc2 += hv.x * wB[g].x + hv.y * wB[g].y + hv.z * wB[g].z + hv.w * wB[g].w;
        }
        acc2 = fmaxf(acc2, 0.f);
        if (lane < 32) *(float*)(smem + OFF_H2 + o * 4) = acc2;
        wave_fence();

        if (lane < 3) {
            float acc3 = b3v;
            #pragma unroll
            for (int g = 0; g < 8; g++) {
                f32x4 hv = *(const f32x4*)(smem + OFF_H2 + g * 16);
                acc3 += hv.x * wC[g].x + hv.y * wC[g].y + hv.z * wC[g].z + hv.w * wC[g].w;
            }
            out[b * 3 + lane] = acc3;
        }
    }
}

extern "C" void kernel_launch(void* const* d_in, const int* in_sizes, int n_in,
                              void* d_out, int out_size, void* d_ws, size_t ws_size,
                              hipStream_t stream) {
    const float* emb    = (const float*)d_in[0];
    const float* conv_w = (const float*)d_in[1];
    const float* conv_b = (const float*)d_in[2];
    const float* ppw_w  = (const float*)d_in[3];
    const float* ppw_b  = (const float*)d_in[4];
    const float* pdw_w  = (const float*)d_in[5];
    const float* pdw_b  = (const float*)d_in[6];
    const float* pf_w   = (const float*)d_in[7];
    const float* vpw_w  = (const float*)d_in[8];
    const float* vpw_b  = (const float*)d_in[9];
    const float* vl1_w  = (const float*)d_in[10];
    const float* vl1_b  = (const float*)d_in[11];
    const float* vl2_w  = (const float*)d_in[12];
    const float* vl2_b  = (const float*)d_in[13];
    const float* vf_w   = (const float*)d_in[14];
    const float* vf_b   = (const float*)d_in[15];
    const int* sparse   = (const int*)d_in[16];
    const int* board    = (const int*)d_in[17];
    float* out = (float*)d_out;

    int batch = in_sizes[16] / 2700;  // 4096
    patnet_kernel<<<batch, NT, 0, stream>>>(
        emb, conv_w, conv_b, ppw_w, ppw_b, pdw_w, pdw_b, pf_w,
        vpw_w, vpw_b, vl1_w, vl1_b, vl2_w, vl2_b, vf_w, vf_b,
        sparse, board, out, batch);
}

// Round 4
// 168.336 us; speedup vs baseline: 1.1082x; 1.1082x over previous
//
#include <hip/hip_runtime.h>
#include <hip/hip_fp16.h>

typedef _Float16 half8  __attribute__((ext_vector_type(8)));
typedef _Float16 half4_t __attribute__((ext_vector_type(4)));
typedef _Float16 half2_t __attribute__((ext_vector_type(2)));
typedef float f32x4 __attribute__((ext_vector_type(4)));

namespace {
constexpr int NT = 256;
constexpr int NPIX = 225;
constexpr int PCODE_C = 2380;

// A[6][15 rows][17 cols] half8 slots; col0/col16 zero x-pads
constexpr int AROW = 272;   // 17 slots * 16 B
constexpr int ACG  = 4080;  // 15 rows * 272

// ---- LDS layout (byte offsets), 5 blocks/CU plan (63 granules = 32256) ----
// P1 writes A[0..5] (0..24480)
// phase a: conv cg4,5 (reg weights) -> XC4/XC5 fresh; stage SLOTB(cg23) in tail
// phase b: conv cg2,3 -> XC2/XC3 over dead A[4,5]; stage SLOT2(cg01) in A[5] tail
// phase c: conv cg0,1 -> XC0/XC1 over dead A[2,3]; stage SLOTP(pdw) in A[3] tail
// heads:  POLA over dead A[0,1]; SV/H1/H2 over dead SLOT2 region
constexpr int OFF_A     = 0;        // 6*4080 = 24480
constexpr int OFF_POLA0 = 0;        // heads
constexpr int OFF_POLA1 = 4080;
constexpr int OFF_XC0   = 8160;     // 225*16 = 3600 per cg
constexpr int OFF_XC1   = 11760;
constexpr int OFF_SLOTP = 15360;    // 320: pol dw wts (written phase c, read heads)
constexpr int OFF_XC2   = 16320;
constexpr int OFF_XC3   = 19920;
constexpr int OFF_SLOT2 = 23520;    // 320: cg0,1 conv wts (written phase b, read phase c)
constexpr int OFF_SV    = 23840;    // f32[32] (heads, over dead SLOT2 tail region)
constexpr int OFF_H1    = 23968;
constexpr int OFF_H2    = 24096;    // ends 24224 <= 24480
constexpr int OFF_XC4   = 24480;
constexpr int OFF_XC5   = 28080;
constexpr int OFF_ZROW  = 31680;    // 112 B zeros (y-edge rows read ZROW + c*16)
constexpr int OFF_SLOTB = 31792;    // 320: cg2,3 conv wts (written phase a, read phase b)
constexpr int SMEM_BYTES = 32112;   // -> 32256 granule; 5*32256 = 161280 <= 163840
}

__device__ __forceinline__ half2_t pkrtz(float a, float b) {
    return __builtin_bit_cast(half2_t, __builtin_amdgcn_cvt_pkrtz(a, b));
}
__device__ __forceinline__ void wave_fence() {
    asm volatile("s_waitcnt lgkmcnt(0)" ::: "memory");
}

__global__ __launch_bounds__(NT, 4) void patnet_kernel(
    const float* __restrict__ emb,
    const float* __restrict__ conv_w, const float* __restrict__ conv_b,
    const float* __restrict__ ppw_w,  const float* __restrict__ ppw_b,
    const float* __restrict__ pdw_w,  const float* __restrict__ pdw_b,
    const float* __restrict__ pf_w,
    const float* __restrict__ vpw_w,  const float* __restrict__ vpw_b,
    const float* __restrict__ vl1_w,  const float* __restrict__ vl1_b,
    const float* __restrict__ vl2_w,  const float* __restrict__ vl2_b,
    const float* __restrict__ vf_w,   const float* __restrict__ vf_b,
    const int* __restrict__ sparse,   const int* __restrict__ board,
    float* __restrict__ out, int batch)
{
    __shared__ __align__(16) unsigned char smem[SMEM_BYTES];
    const int tid  = threadIdx.x;
    const int b    = blockIdx.x;
    const int lane = tid & 63;
    const int wave = tid >> 6;
    const bool isStrip = tid < 90;

    // ---- issue code loads first (deep prefetch) ----
    int c0 = 0, c1 = 0;
    if (tid < NPIX) {
        int s10 = sparse[b * 2700 + 10 * NPIX + tid];
        int s11 = sparse[b * 2700 + 11 * NPIX + tid];
        int b0  = board[b * 450 + tid];
        int b1  = board[b * 450 + NPIX + tid];
        c0 = (b0 > 0) ? PCODE_C : s10;
        c1 = ((b1 > 0) ? PCODE_C : s11) + (PCODE_C + 1);
    }

    // ---- phase-a (cg4,5) conv weights -> registers; loads hide under gather ----
    f32x4 wrA[18]; f32x4 brA0, brA1;
    const int cgA = 4 + (tid / 45);         // only meaningful for tid<90
    if (isStrip) {
        const float* wp = conv_w + cgA * 72;
        #pragma unroll
        for (int g = 0; g < 18; g++) wrA[g] = *(const f32x4*)(wp + g * 4);
        brA0 = *(const f32x4*)(conv_b + cgA * 8);
        brA1 = *(const f32x4*)(conv_b + cgA * 8 + 4);
    }

    // stage 2 cgs of (dw weights + bias) transposed into a 320 B slot (threads 96+)
    auto stage_w = [&](int slotOff, const float* wsrc, const float* bsrc, int cgbase) {
        int i = tid - 96;
        if (i >= 0 && i < 160) {
            int cgl = i / 80, r = i - cgl * 80;
            _Float16 v;
            if (r < 72) {
                int t = r >> 3, j = r & 7;
                v = (_Float16)wsrc[((cgbase + cgl) * 8 + j) * 9 + t];
            } else {
                v = (_Float16)bsrc[(cgbase + cgl) * 8 + (r - 72)];
            }
            ((_Float16*)(smem + slotOff))[i] = v;
        }
    };

    // ---- P0: threads 160..255 zero A x-pads + ZROW ----
    if (tid >= 160) {
        for (int i = tid - 160; i < 187; i += 96) {
            unsigned char* dst;
            if (i < 180) {            // A col pads: cols 0,16 x rows 0..14 x 6 cg
                int cg = i / 30, r = i - cg * 30;
                int row = r >> 1, colB = (r & 1) * 256;
                dst = smem + OFF_A + cg * ACG + row * AROW + colB;
            } else {                  // zero row: 7 slots (112 B)
                dst = smem + OFF_ZROW + (i - 180) * 16;
            }
            *(half8*)dst = (half8)(_Float16)0.f;
        }
    }

    // ---- P1: embedding gather + sum -> A interior (rows 0..14, cols 1..15) ----
    if (tid < NPIX) {
        const float* e0 = emb + c0 * 48;
        const float* e1 = emb + c1 * 48;
        int y = tid / 15, x = tid - y * 15;
        unsigned char* abase = smem + OFF_A + y * AROW + (x + 1) * 16;
        #pragma unroll
        for (int g = 0; g < 6; g++) {
            f32x4 x0 = *(const f32x4*)(e0 + g * 8);
            f32x4 x1 = *(const f32x4*)(e0 + g * 8 + 4);
            f32x4 y0 = *(const f32x4*)(e1 + g * 8);
            f32x4 y1 = *(const f32x4*)(e1 + g * 8 + 4);
            f32x4 s0 = x0 + y0, s1 = x1 + y1;
            half2_t q0 = pkrtz(s0.x, s0.y), q1 = pkrtz(s0.z, s0.w);
            half2_t q2 = pkrtz(s1.x, s1.y), q3 = pkrtz(s1.z, s1.w);
            half8 hv = {q0[0], q0[1], q1[0], q1[1], q2[0], q2[1], q3[0], q3[1]};
            *(half8*)(abase + g * ACG) = hv;
        }
    }

    // ---- build transposed phase-a weight fragments (fully static indexing) ----
    half8 wvA[9]; half8 biasA;
    if (isStrip) {
        #define WEL(j,t) (_Float16)wrA[((j)*9+(t)) >> 2][((j)*9+(t)) & 3]
        #define WROW(t) wvA[t] = half8{WEL(0,t),WEL(1,t),WEL(2,t),WEL(3,t),WEL(4,t),WEL(5,t),WEL(6,t),WEL(7,t)}
        WROW(0); WROW(1); WROW(2); WROW(3); WROW(4); WROW(5); WROW(6); WROW(7); WROW(8);
        #undef WROW
        #undef WEL
        biasA = half8{(_Float16)brA0.x, (_Float16)brA0.y, (_Float16)brA0.z, (_Float16)brA0.w,
                      (_Float16)brA1.x, (_Float16)brA1.y, (_Float16)brA1.z, (_Float16)brA1.w};
    }
    __syncthreads();

    // ---- conv 3x3 depthwise core (weights passed in; y-edges read ZROW) ----
    auto strip_core = [&](const unsigned char* abase, unsigned char* xw,
                          const half8 (&wv)[9], half8 bias, int y, int s) {
        int xo = s * 80;
        const unsigned char* r0 = (y >= 1)  ? abase + (y - 1) * AROW + xo : smem + OFF_ZROW;
        const unsigned char* r1 = abase + y * AROW + xo;
        const unsigned char* r2 = (y <= 13) ? abase + (y + 1) * AROW + xo : smem + OFF_ZROW;
        half8 acc[5] = {bias, bias, bias, bias, bias};
        #pragma unroll
        for (int c = 0; c < 7; c++) {
            half8 v0 = *(const half8*)(r0 + c * 16);
            half8 v1 = *(const half8*)(r1 + c * 16);
            half8 v2 = *(const half8*)(r2 + c * 16);
            #pragma unroll
            for (int o = 0; o < 5; o++) {
                int kx = c - o;
                if (kx >= 0 && kx <= 2) {
                    acc[o] = __builtin_elementwise_fma(v0, wv[kx],     acc[o]);
                    acc[o] = __builtin_elementwise_fma(v1, wv[3 + kx], acc[o]);
                    acc[o] = __builtin_elementwise_fma(v2, wv[6 + kx], acc[o]);
                }
            }
        }
        #pragma unroll
        for (int o = 0; o < 5; o++)
            *(half8*)(xw + o * 16) = __builtin_elementwise_max(acc[o], (half8)(_Float16)0.f);
    };
    auto load_slot = [&](int slotOff, int cgl, half8 (&wv)[9], half8& bias) {
        #pragma unroll
        for (int i = 0; i < 9; i++) wv[i] = *(const half8*)(smem + slotOff + cgl * 160 + i * 16);
        bias = *(const half8*)(smem + slotOff + cgl * 160 + 144);
    };

    int cgl_s = 0, y_s = 0, s_s = 0;
    if (isStrip) {
        cgl_s = tid / 45;
        int rem = tid - cgl_s * 45;
        y_s = rem / 3; s_s = rem - y_s * 3;
    }

    // phase a: cg4,5 with register weights -> XC4/XC5 fresh
    if (isStrip)
        strip_core(smem + OFF_A + (4 + cgl_s) * ACG,
                   smem + OFF_XC4 + cgl_s * 3600 + (y_s * 15 + s_s * 5) * 16,
                   wvA, biasA, y_s, s_s);
    stage_w(OFF_SLOTB, conv_w, conv_b, 2);
    __syncthreads();

    // phase b: cg2,3 from SLOTB -> XC2/XC3 over dead A[4,5]
    if (isStrip) {
        half8 wv[9]; half8 bias;
        load_slot(OFF_SLOTB, cgl_s, wv, bias);
        strip_core(smem + OFF_A + (2 + cgl_s) * ACG,
                   smem + OFF_XC2 + cgl_s * 3600 + (y_s * 15 + s_s * 5) * 16,
                   wv, bias, y_s, s_s);
    }
    stage_w(OFF_SLOT2, conv_w, conv_b, 0);
    __syncthreads();

    // phase c: cg0,1 from SLOT2 -> XC0/XC1 over dead A[2,3]
    if (isStrip) {
        half8 wv[9]; half8 bias;
        load_slot(OFF_SLOT2, cgl_s, wv, bias);
        strip_core(smem + OFF_A + cgl_s * ACG,
                   smem + OFF_XC0 + cgl_s * 3600 + (y_s * 15 + s_s * 5) * 16,
                   wv, bias, y_s, s_s);
    }
    stage_w(OFF_SLOTP, pdw_w, pdw_b, 0);                  // policy dw -> SLOTP

    // ---- head-weight prefetch by ALL waves (loads fly before barrier drain) ----
    const int n = lane & 15, q = lane >> 4;
    const int cgp = lane & 1;
    half8 af_p;
    {
        const float* wp = ppw_w + n * 16 + (q & 1) * 8;
        f32x4 w0 = *(const f32x4*)wp, w1 = *(const f32x4*)(wp + 4);
        half8 t = {(_Float16)w0.x, (_Float16)w0.y, (_Float16)w0.z, (_Float16)w0.w,
                   (_Float16)w1.x, (_Float16)w1.y, (_Float16)w1.z, (_Float16)w1.w};
        af_p = (q < 2) ? t : (half8)(_Float16)0.f;   // K zero-pad 16..31
    }
    f32x4 pb = *(const f32x4*)(ppw_b + q * 4);
    half2_t pf0 = pkrtz(pf_w[cgp * 8 + 0], pf_w[cgp * 8 + 1]);
    half2_t pf1 = pkrtz(pf_w[cgp * 8 + 2], pf_w[cgp * 8 + 3]);
    half2_t pf2 = pkrtz(pf_w[cgp * 8 + 4], pf_w[cgp * 8 + 5]);
    half2_t pf3 = pkrtz(pf_w[cgp * 8 + 6], pf_w[cgp * 8 + 7]);
    half8 af0, af1;
    {
        const float* wp = vpw_w + n * 32 + q * 8;
        f32x4 w0 = *(const f32x4*)wp, w1 = *(const f32x4*)(wp + 4);
        af0 = half8{(_Float16)w0.x, (_Float16)w0.y, (_Float16)w0.z, (_Float16)w0.w,
                    (_Float16)w1.x, (_Float16)w1.y, (_Float16)w1.z, (_Float16)w1.w};
        const float* wp2 = vpw_w + (16 + n) * 32 + q * 8;
        f32x4 v0 = *(const f32x4*)wp2, v1 = *(const f32x4*)(wp2 + 4);
        af1 = half8{(_Float16)v0.x, (_Float16)v0.y, (_Float16)v0.z, (_Float16)v0.w,
                    (_Float16)v1.x, (_Float16)v1.y, (_Float16)v1.z, (_Float16)v1.w};
    }
    f32x4 vb0 = *(const f32x4*)(vpw_b + q * 4);
    f32x4 vb1 = *(const f32x4*)(vpw_b + 16 + q * 4);
    __syncthreads();

    // ================= head split: no more block barriers =================
    if (wave < 3) {
        // ---------------- policy path (waves 0,1,2) ----------------
        if (lane < 60) {       // zero POLA x-pads (idempotent per wave)
            int cg = lane / 30, r = lane - cg * 30;
            int row = r >> 1, colB = (r & 1) * 256;
            *(half8*)(smem + OFF_POLA0 + cg * ACG + row * AROW + colB) = (half8)(_Float16)0.f;
        }
        half8 wvp[9];
        #pragma unroll
        for (int t = 0; t < 9; t++) wvp[t] = *(const half8*)(smem + OFF_SLOTP + cgp * 160 + t * 16);
        half8 biasp = *(const half8*)(smem + OFF_SLOTP + cgp * 160 + 144);

        // ph3: 1x1 16->16 via MFMA; each wave computes every tile its ph4 rows need
        const int tlo = (wave == 0) ? 0 : ((wave == 1) ? 3 : 8);
        const int thi = (wave == 0) ? 6 : ((wave == 1) ? 11 : 15);
        const int cg3 = q >> 1;
        const int xbp = (q & 1) ? OFF_XC1 : OFF_XC0;
        for (int t = tlo; t < thi; t++) {
            int p = t * 16 + n;
            int pc = (p > 224) ? 224 : p;
            half8 bf = *(const half8*)(smem + xbp + pc * 16);
            f32x4 d = __builtin_amdgcn_mfma_f32_16x16x32_f16(af_p, bf, (f32x4)(0.f), 0, 0, 0);
            if (p < NPIX) {
                int y = p / 15, x = p - y * 15;
                half2_t lo = pkrtz(fmaxf(d.x + pb.x, 0.f), fmaxf(d.y + pb.y, 0.f));
                half2_t hi = pkrtz(fmaxf(d.z + pb.z, 0.f), fmaxf(d.w + pb.w, 0.f));
                half4_t hv = {lo[0], lo[1], hi[0], hi[1]};
                *(half4_t*)(smem + OFF_POLA0 + cg3 * ACG + y * AROW + (x + 1) * 16 + (q & 1) * 8) = hv;
            }
        }
        wave_fence();

        // ph4+ph5 fused: dw 3x3 + bias + relu + dot(pf) + pair-sum + store
        const int px0 = wave * 75;
        for (int i = 0; i < 3; i++) {
            int idx = i * 64 + lane;
            if (idx < 150) {
                int px = px0 + (idx >> 1);
                int y = px / 15, x = px - y * 15;
                const unsigned char* base = smem + OFF_POLA0 + cgp * ACG;
                int xo = x * 16;
                const unsigned char* pm = (y > 0)  ? base + (y - 1) * AROW + xo : smem + OFF_ZROW;
                const unsigned char* pz = base + y * AROW + xo;
                const unsigned char* pp = (y < 14) ? base + (y + 1) * AROW + xo : smem + OFF_ZROW;
                half8 acc = biasp;
                acc = __builtin_elementwise_fma(*(const half8*)(pm),      wvp[0], acc);
                acc = __builtin_elementwise_fma(*(const half8*)(pm + 16), wvp[1], acc);
                acc = __builtin_elementwise_fma(*(const half8*)(pm + 32), wvp[2], acc);
                acc = __builtin_elementwise_fma(*(const half8*)(pz),      wvp[3], acc);
                acc = __builtin_elementwise_fma(*(const half8*)(pz + 16), wvp[4], acc);
                acc = __builtin_elementwise_fma(*(const half8*)(pz + 32), wvp[5], acc);
                acc = __builtin_elementwise_fma(*(const half8*)(pp),      wvp[6], acc);
                acc = __builtin_elementwise_fma(*(const half8*)(pp + 16), wvp[7], acc);
                acc = __builtin_elementwise_fma(*(const half8*)(pp + 32), wvp[8], acc);
                acc = __builtin_elementwise_max(acc, (half8)(_Float16)0.f);
                float part = 0.f;
                part = __builtin_amdgcn_fdot2(half2_t{acc[0], acc[1]}, pf0, part, false);
                part = __builtin_amdgcn_fdot2(half2_t{acc[2], acc[3]}, pf1, part, false);
                part = __builtin_amdgcn_fdot2(half2_t{acc[4], acc[5]}, pf2, part, false);
                part = __builtin_amdgcn_fdot2(half2_t{acc[6], acc[7]}, pf3, part, false);
                float tot = part + __shfl_xor(part, 1, 64);
                if (cgp == 0) out[3 * batch + b * NPIX + px] = tot;
            }
        }
    } else {
        // ---------------- value path (wave 3, whole head in-wave) ----------------
        // B reads ch 16..47: q=0 -> XC2, q=1 -> XC3, q=2 -> XC4, q=3 -> XC5
        const int xb = (q < 2) ? (OFF_XC2 + q * 3600) : (OFF_XC4 + (q - 2) * 3600);
        f32x4 a0 = {0.f, 0.f, 0.f, 0.f}, a1 = {0.f, 0.f, 0.f, 0.f};
        for (int t = 0; t < 15; t++) {
            int p = t * 16 + n;
            int pc = (p > 224) ? 224 : p;
            half8 bf = *(const half8*)(smem + xb + pc * 16);
            f32x4 d0 = __builtin_amdgcn_mfma_f32_16x16x32_f16(af0, bf, (f32x4)(0.f), 0, 0, 0);
            f32x4 d1 = __builtin_amdgcn_mfma_f32_16x16x32_f16(af1, bf, (f32x4)(0.f), 0, 0, 0);
            if (p < NPIX) {
                #pragma unroll
                for (int r = 0; r < 4; r++) {
                    a0[r] += fmaxf(d0[r] + vb0[r], 0.f);
                    a1[r] += fmaxf(d1[r] + vb1[r], 0.f);
                }
            }
        }
        #pragma unroll
        for (int s = 1; s < 16; s <<= 1) {
            #pragma unroll
            for (int r = 0; r < 4; r++) {
                a0[r] += __shfl_xor(a0[r], s, 64);
                a1[r] += __shfl_xor(a1[r], s, 64);
            }
        }
        if (n == 0) {
            *(f32x4*)(smem + OFF_SV + q * 16)      = a0 * (1.f / 225.f);
            *(f32x4*)(smem + OFF_SV + 64 + q * 16) = a1 * (1.f / 225.f);
        }
        // FC weights staged ONE phase ahead (peak live = 64 weight VGPRs, no spill)
        const int o = lane & 31;
        f32x4 wA[8];
        float b1v = vl1_b[o], b2v = vl2_b[o], b3v = 0.f;
        #pragma unroll
        for (int g = 0; g < 8; g++) wA[g] = *(const f32x4*)(vl1_w + o * 32 + g * 4);
        wave_fence();                                  // SV visible wave-wide

        f32x4 wB[8];
        #pragma unroll
        for (int g = 0; g < 8; g++) wB[g] = *(const f32x4*)(vl2_w + o * 32 + g * 4);
        float acc1 = b1v;
        #pragma unroll
        for (int g = 0; g < 8; g++) {
            f32x4 sv = *(const f32x4*)(smem + OFF_SV + g * 16);
            acc1 += sv.x * wA[g].x + sv.y * wA[g].y + sv.z * wA[g].z + sv.w * wA[g].w;
        }
        acc1 = fmaxf(acc1, 0.f);
        if (lane < 32) *(float*)(smem + OFF_H1 + o * 4) = acc1;
        wave_fence();

        f32x4 wC[8];
        if (lane < 3) {
            b3v = vf_b[lane];
            #pragma unroll
            for (int g = 0; g < 8; g++) wC[g] = *(const f32x4*)(vf_w + lane * 32 + g * 4);
        }
        float acc2 = b2v;
        #pragma unroll
        for (int g = 0; g < 8; g++) {
            f32x4 hv = *(const f32x4*)(smem + OFF_H1 + g * 16);
            acc2 += hv.x * wB[g].x + hv.y * wB[g].y + hv.z * wB[g].z + hv.w * wB[g].w;
        }
        acc2 = fmaxf(acc2, 0.f);
        if (lane < 32) *(float*)(smem + OFF_H2 + o * 4) = acc2;
        wave_fence();

        if (lane < 3) {
            float acc3 = b3v;
            #pragma unroll
            for (int g = 0; g < 8; g++) {
                f32x4 hv = *(const f32x4*)(smem + OFF_H2 + g * 16);
                acc3 += hv.x * wC[g].x + hv.y * wC[g].y + hv.z * wC[g].z + hv.w * wC[g].w;
            }
            out[b * 3 + lane] = acc3;
        }
    }
}

extern "C" void kernel_launch(void* const* d_in, const int* in_sizes, int n_in,
                              void* d_out, int out_size, void* d_ws, size_t ws_size,
                              hipStream_t stream) {
    const float* emb    = (const float*)d_in[0];
    const float* conv_w = (const float*)d_in[1];
    const float* conv_b = (const float*)d_in[2];
    const float* ppw_w  = (const float*)d_in[3];
    const float* ppw_b  = (const float*)d_in[4];
    const float* pdw_w  = (const float*)d_in[5];
    const float* pdw_b  = (const float*)d_in[6];
    const float* pf_w   = (const float*)d_in[7];
    const float* vpw_w  = (const float*)d_in[8];
    const float* vpw_b  = (const float*)d_in[9];
    const float* vl1_w  = (const float*)d_in[10];
    const float* vl1_b  = (const float*)d_in[11];
    const float* vl2_w  = (const float*)d_in[12];
    const float* vl2_b  = (const float*)d_in[13];
    const float* vf_w   = (const float*)d_in[14];
    const float* vf_b   = (const float*)d_in[15];
    const int* sparse   = (const int*)d_in[16];
    const int* board    = (const int*)d_in[17];
    float* out = (float*)d_out;

    int batch = in_sizes[16] / 2700;  // 4096
    patnet_kernel<<<batch, NT, 0, stream>>>(
        emb, conv_w, conv_b, ppw_w, ppw_b, pdw_w, pdw_b, pf_w,
        vpw_w, vpw_b, vl1_w, vl1_b, vl2_w, vl2_b, vf_w, vf_b,
        sparse, board, out, batch);
}

// Round 7
// 165.550 us; speedup vs baseline: 1.1269x; 1.0168x over previous
//
#include <hip/hip_runtime.h>
#include <hip/hip_fp16.h>

typedef _Float16 half8  __attribute__((ext_vector_type(8)));
typedef _Float16 half4_t __attribute__((ext_vector_type(4)));
typedef _Float16 half2_t __attribute__((ext_vector_type(2)));
typedef float f32x4 __attribute__((ext_vector_type(4)));

namespace {
constexpr int NT = 256;
constexpr int NPIX = 225;
constexpr int PCODE_C = 2380;

// A[6][15 rows][17 cols] half8 slots; col0/col16 zero x-pads
constexpr int AROW = 272;   // 17 slots * 16 B
constexpr int ACG  = 4080;  // 15 rows * 272

// ---- LDS layout (byte offsets), 4 blocks/CU, 2-phase conv, 225-wide phases ----
// P1 writes A[0..5] (0..24480)
// phase a: conv cg3,4,5 reads A[3..5] -> XHI [225][48] fresh (24480..35280)
// phase b: conv cg0,1,2 reads A[0..2] -> XLO [225][48] over dead A[3..5]
// heads:  POLA over dead A[0,1]; SV/H1/H2 over dead A[5] tail; X live
// tail (persistent): ZROW + all weight slots, staged once in P0
constexpr int OFF_A     = 0;        // 6*4080 = 24480
constexpr int OFF_POLA0 = 0;        // heads: 2*4080 = 8160
constexpr int OFF_XLO   = 12240;    // [225][48] = 10800 over A[3..5], ends 23040
constexpr int OFF_SV    = 23040;    // f32[32] (heads only, dead A[5] tail)
constexpr int OFF_H1    = 23168;
constexpr int OFF_H2    = 23296;    // ends 23424 <= 24480
constexpr int OFF_XHI   = 24480;    // [225][48] = 10800, ends 35280
constexpr int OFF_ZROW  = 35280;    // 112 B zeros (y-edge rows read ZROW + c*16, c<=4)
constexpr int OFF_WS    = 35392;    // conv dw wts: 6 cg x (144 w + 16 b) = 960
constexpr int OFF_SLOTP = 36352;    // pol dw wts: 2 cg x 160 = 320
constexpr int SMEM_BYTES = 36672;   // -> 36864 granule; 4*36864 = 147456 <= 163840
}

__device__ __forceinline__ half2_t pkrtz(float a, float b) {
    return __builtin_bit_cast(half2_t, __builtin_amdgcn_cvt_pkrtz(a, b));
}
__device__ __forceinline__ void wave_fence() {
    asm volatile("s_waitcnt lgkmcnt(0)" ::: "memory");
}

__global__ __launch_bounds__(NT, 4) void patnet_kernel(
    const float* __restrict__ emb,
    const float* __restrict__ conv_w, const float* __restrict__ conv_b,
    const float* __restrict__ ppw_w,  const float* __restrict__ ppw_b,
    const float* __restrict__ pdw_w,  const float* __restrict__ pdw_b,
    const float* __restrict__ pf_w,
    const float* __restrict__ vpw_w,  const float* __restrict__ vpw_b,
    const float* __restrict__ vl1_w,  const float* __restrict__ vl1_b,
    const float* __restrict__ vl2_w,  const float* __restrict__ vl2_b,
    const float* __restrict__ vf_w,   const float* __restrict__ vf_b,
    const int* __restrict__ sparse,   const int* __restrict__ board,
    float* __restrict__ out, int batch)
{
    __shared__ __align__(16) unsigned char smem[SMEM_BYTES];
    const int tid  = threadIdx.x;
    const int b    = blockIdx.x;
    const int lane = tid & 63;
    const int wave = tid >> 6;

    // ---- issue code loads first (deep prefetch) ----
    int c0 = 0, c1 = 0;
    if (tid < NPIX) {
        int s10 = sparse[b * 2700 + 10 * NPIX + tid];
        int s11 = sparse[b * 2700 + 11 * NPIX + tid];
        int b0  = board[b * 450 + tid];
        int b1  = board[b * 450 + NPIX + tid];
        c0 = (b0 > 0) ? PCODE_C : s10;
        c1 = ((b1 > 0) ? PCODE_C : s11) + (PCODE_C + 1);
    }

    // ---- P0: stage ALL weight slots (transposed) + zero pads; loads fly
    //      while the gather waits on the code loads above ----
    {
        _Float16* WS = (_Float16*)(smem + OFF_WS);
        for (int i = tid; i < 480; i += NT) {       // conv dw: [cg]{w[t][j], b[j]}
            int cg = i / 80, r = i - cg * 80;
            _Float16 v;
            if (r < 72) { int t = r >> 3, j = r & 7; v = (_Float16)conv_w[(cg * 8 + j) * 9 + t]; }
            else        { v = (_Float16)conv_b[cg * 8 + (r - 72)]; }
            WS[i] = v;
        }
        _Float16* WP = (_Float16*)(smem + OFF_SLOTP);
        if (tid < 160) {                             // pol dw: [cg]{w,b}
            int cg = tid / 80, r = tid - cg * 80;
            _Float16 v;
            if (r < 72) { int t = r >> 3, j = r & 7; v = (_Float16)pdw_w[(cg * 8 + j) * 9 + t]; }
            else        { v = (_Float16)pdw_b[cg * 8 + (r - 72)]; }
            WP[tid] = v;
        }
        if (tid < 187) {                             // zero A x-pads + ZROW
            unsigned char* dst;
            if (tid < 180) {      // cols 0,16 x rows 0..14 x 6 cg
                int cg = tid / 30, r = tid - cg * 30;
                int row = r >> 1, colB = (r & 1) * 256;
                dst = smem + OFF_A + cg * ACG + row * AROW + colB;
            } else {
                dst = smem + OFF_ZROW + (tid - 180) * 16;
            }
            *(half8*)dst = (half8)(_Float16)0.f;
        }
    }

    // ---- P1: embedding gather + sum -> A interior (rows 0..14, cols 1..15) ----
    if (tid < NPIX) {
        const float* e0 = emb + c0 * 48;
        const float* e1 = emb + c1 * 48;
        int y = tid / 15, x = tid - y * 15;
        unsigned char* abase = smem + OFF_A + y * AROW + (x + 1) * 16;
        #pragma unroll
        for (int g = 0; g < 6; g++) {
            f32x4 x0 = *(const f32x4*)(e0 + g * 8);
            f32x4 x1 = *(const f32x4*)(e0 + g * 8 + 4);
            f32x4 y0 = *(const f32x4*)(e1 + g * 8);
            f32x4 y1 = *(const f32x4*)(e1 + g * 8 + 4);
            f32x4 s0 = x0 + y0, s1 = x1 + y1;
            half2_t q0 = pkrtz(s0.x, s0.y), q1 = pkrtz(s0.z, s0.w);
            half2_t q2 = pkrtz(s1.x, s1.y), q3 = pkrtz(s1.z, s1.w);
            half8 hv = {q0[0], q0[1], q1[0], q1[1], q2[0], q2[1], q3[0], q3[1]};
            *(half8*)(abase + g * ACG) = hv;
        }
    }
    __syncthreads();

    // ---- conv 3x3 depthwise: 2 phases x 3 cgs; 225 3-px-strip tasks per phase ----
    // task t: cgl = t/75, y = (t%75)/5, s = (t%75)%5, output cols 3s..3s+2
    auto do_strip = [&](int t, int cgbase, int xBase) {
        int cgl = t / 75, rem = t - cgl * 75;
        int y = rem / 5, s = rem - y * 5;
        int cg = cgbase + cgl;
        const unsigned char* wb = smem + OFF_WS + cg * 160;
        half8 wv[9];
        #pragma unroll
        for (int i = 0; i < 9; i++) wv[i] = *(const half8*)(wb + i * 16);
        half8 bias = *(const half8*)(wb + 144);
        const unsigned char* abase = smem + OFF_A + cg * ACG;
        int xo = s * 48;                 // padded col 3s, in bytes
        const unsigned char* r0 = (y >= 1)  ? abase + (y - 1) * AROW + xo : smem + OFF_ZROW;
        const unsigned char* r1 = abase + y * AROW + xo;
        const unsigned char* r2 = (y <= 13) ? abase + (y + 1) * AROW + xo : smem + OFF_ZROW;
        half8 acc[3] = {bias, bias, bias};
        #pragma unroll
        for (int c = 0; c < 5; c++) {
            half8 v0 = *(const half8*)(r0 + c * 16);
            half8 v1 = *(const half8*)(r1 + c * 16);
            half8 v2 = *(const half8*)(r2 + c * 16);
            #pragma unroll
            for (int o = 0; o < 3; o++) {
                int kx = c - o;
                if (kx >= 0 && kx <= 2) {
                    acc[o] = __builtin_elementwise_fma(v0, wv[kx],     acc[o]);
                    acc[o] = __builtin_elementwise_fma(v1, wv[3 + kx], acc[o]);
                    acc[o] = __builtin_elementwise_fma(v2, wv[6 + kx], acc[o]);
                }
            }
        }
        unsigned char* xw = smem + xBase + (y * 15 + s * 3) * 48 + cgl * 16;
        #pragma unroll
        for (int o = 0; o < 3; o++)
            *(half8*)(xw + o * 48) = __builtin_elementwise_max(acc[o], (half8)(_Float16)0.f);
    };

    if (tid < 225) do_strip(tid, 3, OFF_XHI);   // phase a: cg3..5 -> XHI fresh
    __syncthreads();
    if (tid < 225) do_strip(tid, 0, OFF_XLO);   // phase b: cg0..2 -> XLO over dead A[3..5]

    // ---- head-weight prefetch by ALL waves (loads fly before barrier drain) ----
    const int n = lane & 15, q = lane >> 4;
    const int cgp = lane & 1;
    half8 af_p;
    {
        const float* wp = ppw_w + n * 16 + (q & 1) * 8;
        f32x4 w0 = *(const f32x4*)wp, w1 = *(const f32x4*)(wp + 4);
        half8 t = {(_Float16)w0.x, (_Float16)w0.y, (_Float16)w0.z, (_Float16)w0.w,
                   (_Float16)w1.x, (_Float16)w1.y, (_Float16)w1.z, (_Float16)w1.w};
        af_p = (q < 2) ? t : (half8)(_Float16)0.f;   // K zero-pad 16..31
    }
    f32x4 pb = *(const f32x4*)(ppw_b + q * 4);
    half2_t pf0 = pkrtz(pf_w[cgp * 8 + 0], pf_w[cgp * 8 + 1]);
    half2_t pf1 = pkrtz(pf_w[cgp * 8 + 2], pf_w[cgp * 8 + 3]);
    half2_t pf2 = pkrtz(pf_w[cgp * 8 + 4], pf_w[cgp * 8 + 5]);
    half2_t pf3 = pkrtz(pf_w[cgp * 8 + 6], pf_w[cgp * 8 + 7]);
    half8 af0, af1;
    {
        const float* wp = vpw_w + n * 32 + q * 8;
        f32x4 w0 = *(const f32x4*)wp, w1 = *(const f32x4*)(wp + 4);
        af0 = half8{(_Float16)w0.x, (_Float16)w0.y, (_Float16)w0.z, (_Float16)w0.w,
                    (_Float16)w1.x, (_Float16)w1.y, (_Float16)w1.z, (_Float16)w1.w};
        const float* wp2 = vpw_w + (16 + n) * 32 + q * 8;
        f32x4 v0 = *(const f32x4*)wp2, v1 = *(const f32x4*)(wp2 + 4);
        af1 = half8{(_Float16)v0.x, (_Float16)v0.y, (_Float16)v0.z, (_Float16)v0.w,
                    (_Float16)v1.x, (_Float16)v1.y, (_Float16)v1.z, (_Float16)v1.w};
    }
    f32x4 vb0 = *(const f32x4*)(vpw_b + q * 4);
    f32x4 vb1 = *(const f32x4*)(vpw_b + 16 + q * 4);
    __syncthreads();

    // ================= head split: no more block barriers =================
    if (wave < 3) {
        // ---------------- policy path (waves 0,1,2) ----------------
        if (lane < 60) {       // zero POLA x-pads (idempotent per wave)
            int cg = lane / 30, r = lane - cg * 30;
            int row = r >> 1, colB = (r & 1) * 256;
            *(half8*)(smem + OFF_POLA0 + cg * ACG + row * AROW + colB) = (half8)(_Float16)0.f;
        }
        half8 wvp[9];
        #pragma unroll
        for (int t = 0; t < 9; t++) wvp[t] = *(const half8*)(smem + OFF_SLOTP + cgp * 160 + t * 16);
        half8 biasp = *(const half8*)(smem + OFF_SLOTP + cgp * 160 + 144);

        // ph3: 1x1 16->16 via MFMA; each wave computes every tile its ph4 rows need
        const int tlo = (wave == 0) ? 0 : ((wave == 1) ? 3 : 8);
        const int thi = (wave == 0) ? 6 : ((wave == 1) ? 11 : 15);
        const int cg3 = q >> 1;
        const int xoff = (q & 1) * 16;
        for (int t = tlo; t < thi; t++) {
            int p = t * 16 + n;
            int pc = (p > 224) ? 224 : p;
            half8 bf = *(const half8*)(smem + OFF_XLO + pc * 48 + xoff);
            f32x4 d = __builtin_amdgcn_mfma_f32_16x16x32_f16(af_p, bf, (f32x4)(0.f), 0, 0, 0);
            if (p < NPIX) {
                int y = p / 15, x = p - y * 15;
                half2_t lo = pkrtz(fmaxf(d.x + pb.x, 0.f), fmaxf(d.y + pb.y, 0.f));
                half2_t hi = pkrtz(fmaxf(d.z + pb.z, 0.f), fmaxf(d.w + pb.w, 0.f));
                half4_t hv = {lo[0], lo[1], hi[0], hi[1]};
                *(half4_t*)(smem + OFF_POLA0 + cg3 * ACG + y * AROW + (x + 1) * 16 + (q & 1) * 8) = hv;
            }
        }
        wave_fence();

        // ph4+ph5 fused: dw 3x3 + bias + relu + dot(pf) + pair-sum + store
        const int px0 = wave * 75;
        for (int i = 0; i < 3; i++) {
            int idx = i * 64 + lane;
            if (idx < 150) {
                int px = px0 + (idx >> 1);
                int y = px / 15, x = px - y * 15;
                const unsigned char* base = smem + OFF_POLA0 + cgp * ACG;
                int xo = x * 16;
                const unsigned char* pm = (y > 0)  ? base + (y - 1) * AROW + xo : smem + OFF_ZROW;
                const unsigned char* pz = base + y * AROW + xo;
                const unsigned char* pp = (y < 14) ? base + (y + 1) * AROW + xo : smem + OFF_ZROW;
                half8 acc = biasp;
                acc = __builtin_elementwise_fma(*(const half8*)(pm),      wvp[0], acc);
                acc = __builtin_elementwise_fma(*(const half8*)(pm + 16), wvp[1], acc);
                acc = __builtin_elementwise_fma(*(const half8*)(pm + 32), wvp[2], acc);
                acc = __builtin_elementwise_fma(*(const half8*)(pz),      wvp[3], acc);
                acc = __builtin_elementwise_fma(*(const half8*)(pz + 16), wvp[4], acc);
                acc = __builtin_elementwise_fma(*(const half8*)(pz + 32), wvp[5], acc);
                acc = __builtin_elementwise_fma(*(const half8*)(pp),      wvp[6], acc);
                acc = __builtin_elementwise_fma(*(const half8*)(pp + 16), wvp[7], acc);
                acc = __builtin_elementwise_fma(*(const half8*)(pp + 32), wvp[8], acc);
                acc = __builtin_elementwise_max(acc, (half8)(_Float16)0.f);
                float part = 0.f;
                part = __builtin_amdgcn_fdot2(half2_t{acc[0], acc[1]}, pf0, part, false);
                part = __builtin_amdgcn_fdot2(half2_t{acc[2], acc[3]}, pf1, part, false);
                part = __builtin_amdgcn_fdot2(half2_t{acc[4], acc[5]}, pf2, part, false);
                part = __builtin_amdgcn_fdot2(half2_t{acc[6], acc[7]}, pf3, part, false);
                float tot = part + __shfl_xor(part, 1, 64);
                if (cgp == 0) out[3 * batch + b * NPIX + px] = tot;
            }
        }
    } else {
        // ---------------- value path (wave 3, whole head in-wave) ----------------
        // B reads ch 16..47: q=0 -> XLO col2 (cg2), q=1..3 -> XHI cols 0..2 (cg3..5)
        const int xb = (q == 0) ? (OFF_XLO + 32) : (OFF_XHI + (q - 1) * 16);
        f32x4 a0 = {0.f, 0.f, 0.f, 0.f}, a1 = {0.f, 0.f, 0.f, 0.f};
        for (int t = 0; t < 15; t++) {
            int p = t * 16 + n;
            int pc = (p > 224) ? 224 : p;
            half8 bf = *(const half8*)(smem + xb + pc * 48);
            f32x4 d0 = __builtin_amdgcn_mfma_f32_16x16x32_f16(af0, bf, (f32x4)(0.f), 0, 0, 0);
            f32x4 d1 = __builtin_amdgcn_mfma_f32_16x16x32_f16(af1, bf, (f32x4)(0.f), 0, 0, 0);
            if (p < NPIX) {
                #pragma unroll
                for (int r = 0; r < 4; r++) {
                    a0[r] += fmaxf(d0[r] + vb0[r], 0.f);
                    a1[r] += fmaxf(d1[r] + vb1[r], 0.f);
                }
            }
        }
        #pragma unroll
        for (int s = 1; s < 16; s <<= 1) {
            #pragma unroll
            for (int r = 0; r < 4; r++) {
                a0[r] += __shfl_xor(a0[r], s, 64);
                a1[r] += __shfl_xor(a1[r], s, 64);
            }
        }
        if (n == 0) {
            *(f32x4*)(smem + OFF_SV + q * 16)      = a0 * (1.f / 225.f);
            *(f32x4*)(smem + OFF_SV + 64 + q * 16) = a1 * (1.f / 225.f);
        }
        // FC weights staged ONE phase ahead (peak live = 64 weight VGPRs, no spill)
        const int o = lane & 31;
        f32x4 wA[8];
        float b1v = vl1_b[o], b2v = vl2_b[o], b3v = 0.f;
        #pragma unroll
        for (int g = 0; g < 8; g++) wA[g] = *(const f32x4*)(vl1_w + o * 32 + g * 4);
        wave_fence();                                  // SV visible wave-wide

        f32x4 wB[8];
        #pragma unroll
        for (int g = 0; g < 8; g++) wB[g] = *(const f32x4*)(vl2_w + o * 32 + g * 4);
        float acc1 = b1v;
        #pragma unroll
        for (int g = 0; g < 8; g++) {
            f32x4 sv = *(const f32x4*)(smem + OFF_SV + g * 16);
            acc1 += sv.x * wA[g].x + sv.y * wA[g].y + sv.z * wA[g].z + sv.w * wA[g].w;
        }
        acc1 = fmaxf(acc1, 0.f);
        if (lane < 32) *(float*)(smem + OFF_H1 + o * 4) = acc1;
        wave_fence();

        f32x4 wC[8];
        if (lane < 3) {
            b3v = vf_b[lane];
            #pragma unroll
            for (int g = 0; g < 8; g++) wC[g] = *(const f32x4*)(vf_w + lane * 32 + g * 4);
        }
        float acc2 = b2v;
        #pragma unroll
        for (int g = 0; g < 8; g++) {
            f32x4 hv = *(const f32x4*)(smem + OFF_H1 + g * 16);
            acc2 += hv.x * wB[g].x + hv.y * wB[g].y + hv.z * wB[g].z + hv.w * wB[g].w;
        }
        acc2 = fmaxf(acc2, 0.f);
        if (lane < 32) *(float*)(smem + OFF_H2 + o * 4) = acc2;
        wave_fence();

        if (lane < 3) {
            float acc3 = b3v;
            #pragma unroll
            for (int g = 0; g < 8; g++) {
                f32x4 hv = *(const f32x4*)(smem + OFF_H2 + g * 16);
                acc3 += hv.x * wC[g].x + hv.y * wC[g].y + hv.z * wC[g].z + hv.w * wC[g].w;
            }
            out[b * 3 + lane] = acc3;
        }
    }
}

extern "C" void kernel_launch(void* const* d_in, const int* in_sizes, int n_in,
                              void* d_out, int out_size, void* d_ws, size_t ws_size,
                              hipStream_t stream) {
    const float* emb    = (const float*)d_in[0];
    const float* conv_w = (const float*)d_in[1];
    const float* conv_b = (const float*)d_in[2];
    const float* ppw_w  = (const float*)d_in[3];
    const float* ppw_b  = (const float*)d_in[4];
    const float* pdw_w  = (const float*)d_in[5];
    const float* pdw_b  = (const float*)d_in[6];
    const float* pf_w   = (const float*)d_in[7];
    const float* vpw_w  = (const float*)d_in[8];
    const float* vpw_b  = (const float*)d_in[9];
    const float* vl1_w  = (const float*)d_in[10];
    const float* vl1_b  = (const float*)d_in[11];
    const float* vl2_w  = (const float*)d_in[12];
    const float* vl2_b  = (const float*)d_in[13];
    const float* vf_w   = (const float*)d_in[14];
    const float* vf_b   = (const float*)d_in[15];
    const int* sparse   = (const int*)d_in[16];
    const int* board    = (const int*)d_in[17];
    float* out = (float*)d_out;

    int batch = in_sizes[16] / 2700;  // 4096
    patnet_kernel<<<batch, NT, 0, stream>>>(
        emb, conv_w, conv_b, ppw_w, ppw_b, pdw_w, pdw_b, pf_w,
        vpw_w, vpw_b, vl1_w, vl1_b, vl2_w, vl2_b, vf_w, vf_b,
        sparse, board, out, batch);
}